// Round 13
// baseline (559.563 us; speedup 1.0000x reference)
//
#include <hip/hip_runtime.h>
#include <math.h>

typedef __bf16 bf16;
typedef __attribute__((ext_vector_type(8))) __bf16 bf16x8;
typedef __attribute__((ext_vector_type(4))) float f32x4;

#define NBLK 512      // edge-partition blocks for binning (512 -> 2 blocks/CU; 128 was 0.5)
#define NB_MAX 1600   // max buckets (N/64); N=100000 -> 1563

__device__ __forceinline__ void bn_coeffs(const float* st, const float* g,
                                          const float* be, float inv_n, int d,
                                          float& sc, float& sh) {
  float mean = st[d] * inv_n;
  float var = st[64 + d] * inv_n - mean * mean;
  sc = g[d] * rsqrtf(var + 1e-5f);
  sh = be[d] - mean * sc;
}

// ---------------- edge binning (bucket = dst>>6) ----------------
__global__ __launch_bounds__(256) void bin_hist_kernel(const int* __restrict__ dst,
                                                       int* __restrict__ cnt,
                                                       int E, int ch, int nb) {
  __shared__ int lcnt[NB_MAX];
  int tid = threadIdx.x, blk = blockIdx.x;
  for (int t = tid; t < nb; t += 256) lcnt[t] = 0;
  __syncthreads();
  int base = blk * ch, eend = min(E, base + ch);
  for (int e = base + tid; e < eend; e += 256) atomicAdd(&lcnt[dst[e] >> 6], 1);
  __syncthreads();
  for (int t = tid; t < nb; t += 256) cnt[blk * nb + t] = lcnt[t];
}

__global__ __launch_bounds__(256) void bin_tot_kernel(const int* __restrict__ cnt,
                                                      int* __restrict__ tot, int nb) {
  int b = blockIdx.x * 256 + threadIdx.x;
  if (b >= nb) return;
  int s = 0;
  for (int blk = 0; blk < NBLK; ++blk) s += cnt[blk * nb + b];
  tot[b] = s;
}

__global__ __launch_bounds__(256) void scan_buckets_kernel(const int* __restrict__ tot,
                                                           int* __restrict__ bucketptr, int nb) {
  __shared__ int lds[256];
  int tid = threadIdx.x;
  const int CH = 7;
  int vals[CH];
  int s = 0;
#pragma unroll
  for (int k = 0; k < CH; ++k) {
    int i = tid * CH + k;
    vals[k] = (i < nb) ? tot[i] : 0;
    s += vals[k];
  }
  lds[tid] = s;
  __syncthreads();
  for (int off = 1; off < 256; off <<= 1) {
    int v = (tid >= off) ? lds[tid - off] : 0;
    __syncthreads();
    lds[tid] += v;
    __syncthreads();
  }
  int run = lds[tid] - s;
  if (tid == 0) bucketptr[0] = 0;
#pragma unroll
  for (int k = 0; k < CH; ++k) {
    int i = tid * CH + k;
    run += vals[k];
    if (i < nb) bucketptr[i + 1] = run;
  }
}

__global__ __launch_bounds__(256) void bin_off_kernel(const int* __restrict__ cnt,
                                                      const int* __restrict__ bucketptr,
                                                      int* __restrict__ woff, int nb) {
  int b = blockIdx.x * 256 + threadIdx.x;
  if (b >= nb) return;
  int run = bucketptr[b];
  for (int blk = 0; blk < NBLK; ++blk) {
    woff[blk * nb + b] = run;
    run += cnt[blk * nb + b];
  }
}

__global__ __launch_bounds__(256) void bin_scatter_kernel(const int* __restrict__ src,
                                                          const int* __restrict__ dst,
                                                          const int* __restrict__ woff,
                                                          int* __restrict__ packed,
                                                          int E, int ch, int nb) {
  __shared__ int cur[NB_MAX];
  int tid = threadIdx.x, blk = blockIdx.x;
  for (int t = tid; t < nb; t += 256) cur[t] = woff[blk * nb + t];
  __syncthreads();
  int base = blk * ch, eend = min(E, base + ch);
  for (int e = base + tid; e < eend; e += 256) {
    int d = dst[e], s = src[e];
    int pos = atomicAdd(&cur[d >> 6], 1);
    packed[pos] = ((d & 63) << 17) | s;
  }
}

__global__ __launch_bounds__(256) void csr_finalize_kernel(
    const int* __restrict__ packed, const int* __restrict__ bucketptr,
    int* __restrict__ rowptr, int* __restrict__ colidx, int n, int E) {
  __shared__ int hist[64], offs[64];
  int tid = threadIdx.x, b = blockIdx.x;
  if (tid < 64) hist[tid] = 0;
  __syncthreads();
  int beg = bucketptr[b], end = bucketptr[b + 1];
  for (int e = beg + tid; e < end; e += 256) atomicAdd(&hist[packed[e] >> 17], 1);
  __syncthreads();
  if (tid == 0) {
    int run = 0;
    for (int j = 0; j < 64; ++j) { offs[j] = run; run += hist[j]; }
  }
  __syncthreads();
  if (tid < 64) {
    int idx = b * 64 + tid;
    if (idx < n) rowptr[idx] = beg + offs[tid];
    hist[tid] = offs[tid];
  }
  if (b == 0 && tid == 64) rowptr[n] = E;
  __syncthreads();
  for (int e = beg + tid; e < end; e += 256) {
    int w = packed[e];
    int pos = atomicAdd(&hist[w >> 17], 1);
    colidx[beg + pos] = w & 0x1FFFF;
  }
}

// ------- MFMA GEMM 0 with fused embedding (no x0 materialization) -------
__global__ __launch_bounds__(256) void mfma_gemm0(
    const int* __restrict__ deg, const int* __restrict__ lab,
    const float* __restrict__ ed, const float* __restrict__ el,
    const float* __restrict__ W, bf16* __restrict__ y, int n) {
  __shared__ bf16 As[64][136];
  __shared__ bf16 Bs[64][136];
  int tid = threadIdx.x;
  int nbase = blockIdx.x * 64;
  {
    int r = tid >> 2, c = tid & 3;
    int node = nbase + r;
    union { bf16 hh[32]; uint4 u[4]; } t;
    if (node < n) {
      int idx = (c < 2) ? deg[node] : lab[node];
      const float* srcp = (c < 2) ? (ed + (size_t)idx * 64 + c * 32)
                                  : (el + (size_t)idx * 64 + (c - 2) * 32);
#pragma unroll
      for (int j = 0; j < 8; ++j) {
        float4 f = ((const float4*)srcp)[j];
        t.hh[j * 4 + 0] = (bf16)f.x; t.hh[j * 4 + 1] = (bf16)f.y;
        t.hh[j * 4 + 2] = (bf16)f.z; t.hh[j * 4 + 3] = (bf16)f.w;
      }
    } else {
#pragma unroll
      for (int j = 0; j < 4; ++j) t.u[j] = uint4{0, 0, 0, 0};
    }
#pragma unroll
    for (int j = 0; j < 4; ++j) *(uint4*)&As[r][c * 32 + j * 8] = t.u[j];
    const float4* wp = (const float4*)(W + r * 128 + c * 32);
#pragma unroll
    for (int j = 0; j < 4; ++j) {
      float4 f0 = wp[j * 2], f1 = wp[j * 2 + 1];
      union { bf16 h[8]; uint4 u; } tw;
      tw.h[0] = (bf16)f0.x; tw.h[1] = (bf16)f0.y; tw.h[2] = (bf16)f0.z; tw.h[3] = (bf16)f0.w;
      tw.h[4] = (bf16)f1.x; tw.h[5] = (bf16)f1.y; tw.h[6] = (bf16)f1.z; tw.h[7] = (bf16)f1.w;
      *(uint4*)&Bs[r][c * 32 + j * 8] = tw.u;
    }
  }
  __syncthreads();
  int l = tid & 63, w = tid >> 6, m = l & 15, quad = l >> 4;
  f32x4 acc[4] = {{0.f, 0.f, 0.f, 0.f}, {0.f, 0.f, 0.f, 0.f},
                  {0.f, 0.f, 0.f, 0.f}, {0.f, 0.f, 0.f, 0.f}};
#pragma unroll
  for (int k0 = 0; k0 < 128; k0 += 32) {
    bf16x8 a = *(const bf16x8*)&As[w * 16 + m][k0 + quad * 8];
#pragma unroll
    for (int t = 0; t < 4; ++t) {
      bf16x8 b = *(const bf16x8*)&Bs[t * 16 + m][k0 + quad * 8];
      acc[t] = __builtin_amdgcn_mfma_f32_16x16x32_bf16(a, b, acc[t], 0, 0, 0);
    }
  }
#pragma unroll
  for (int t = 0; t < 4; ++t)
#pragma unroll
    for (int r4 = 0; r4 < 4; ++r4) {
      int node = nbase + w * 16 + quad * 4 + r4;
      if (node < n) y[(size_t)node * 64 + t * 16 + m] = (bf16)acc[t][r4];
    }
}

// ------- MFMA GEMM (layers 1,2) -------
__global__ __launch_bounds__(256) void mfma_gemm_bn(
    const bf16* __restrict__ hin, const float* __restrict__ st,
    const float* __restrict__ g, const float* __restrict__ be, float inv_n,
    const float* __restrict__ W, bf16* __restrict__ z,
    bf16* __restrict__ y, int n) {
  __shared__ bf16 As[64][72];
  __shared__ bf16 Bs[64][72];
  __shared__ float ssc[64], ssh[64];
  int tid = threadIdx.x;
  int nbase = blockIdx.x * 64;
  if (tid < 64) {
    float sc, sh;
    bn_coeffs(st, g, be, inv_n, tid, sc, sh);
    ssc[tid] = sc; ssh[tid] = sh;
  }
  __syncthreads();
  {
    int r = tid >> 2, c = tid & 3;
    int node = nbase + r;
    union { bf16 h[16]; uint4 u[2]; } t;
    if (node < n) {
      const uint4* p = (const uint4*)(hin + (size_t)node * 64 + c * 16);
      union { uint4 u; bf16 h[8]; } a0, a1;
      a0.u = p[0]; a1.u = p[1];
#pragma unroll
      for (int j = 0; j < 8; ++j) {
        int d = c * 16 + j;
        float v = (float)a0.h[j] * ssc[d] + ssh[d];
        v = (v >= 0.f) ? v : 0.01f * v;
        t.h[j] = (bf16)v;
      }
#pragma unroll
      for (int j = 0; j < 8; ++j) {
        int d = c * 16 + 8 + j;
        float v = (float)a1.h[j] * ssc[d] + ssh[d];
        v = (v >= 0.f) ? v : 0.01f * v;
        t.h[8 + j] = (bf16)v;
      }
      *(uint4*)(z + (size_t)node * 64 + c * 16) = t.u[0];
      *(uint4*)(z + (size_t)node * 64 + c * 16 + 8) = t.u[1];
    } else {
      t.u[0] = uint4{0, 0, 0, 0}; t.u[1] = uint4{0, 0, 0, 0};
    }
    *(uint4*)&As[r][c * 16] = t.u[0];
    *(uint4*)&As[r][c * 16 + 8] = t.u[1];
    const float4* wp = (const float4*)(W + r * 64 + c * 16);
#pragma unroll
    for (int j = 0; j < 2; ++j) {
      float4 f0 = wp[j * 2], f1 = wp[j * 2 + 1];
      union { bf16 h[8]; uint4 u; } tw;
      tw.h[0] = (bf16)f0.x; tw.h[1] = (bf16)f0.y; tw.h[2] = (bf16)f0.z; tw.h[3] = (bf16)f0.w;
      tw.h[4] = (bf16)f1.x; tw.h[5] = (bf16)f1.y; tw.h[6] = (bf16)f1.z; tw.h[7] = (bf16)f1.w;
      *(uint4*)&Bs[r][c * 16 + j * 8] = tw.u;
    }
  }
  __syncthreads();
  int l = tid & 63, w = tid >> 6, m = l & 15, quad = l >> 4;
  f32x4 acc[4] = {{0.f, 0.f, 0.f, 0.f}, {0.f, 0.f, 0.f, 0.f},
                  {0.f, 0.f, 0.f, 0.f}, {0.f, 0.f, 0.f, 0.f}};
#pragma unroll
  for (int k0 = 0; k0 < 64; k0 += 32) {
    bf16x8 a = *(const bf16x8*)&As[w * 16 + m][k0 + quad * 8];
#pragma unroll
    for (int t = 0; t < 4; ++t) {
      bf16x8 b = *(const bf16x8*)&Bs[t * 16 + m][k0 + quad * 8];
      acc[t] = __builtin_amdgcn_mfma_f32_16x16x32_bf16(a, b, acc[t], 0, 0, 0);
    }
  }
#pragma unroll
  for (int t = 0; t < 4; ++t)
#pragma unroll
    for (int r4 = 0; r4 < 4; ++r4) {
      int node = nbase + w * 16 + quad * 4 + r4;
      if (node < n) y[(size_t)node * 64 + t * 16 + m] = (bf16)acc[t][r4];
    }
}

// ------- gather: dual-node interleave, each load serves 2 edges (r8 proven version) -------
__global__ __launch_bounds__(256) void gather_kernel(
    const bf16* __restrict__ y, const int* __restrict__ rowptr,
    const int* __restrict__ colidx, const float* __restrict__ bias,
    bf16* __restrict__ h, float* __restrict__ stats, int n) {
  __shared__ float s_sum[64], s_sq[64];
  int tid = threadIdx.x;
  if (tid < 64) { s_sum[tid] = 0.f; s_sq[tid] = 0.f; }
  __syncthreads();
  int lane = tid & 63, wv = tid >> 6;
  int half = lane >> 5;  // which edge of the pair
  int lh = lane & 31;    // dim pair 2*lh, 2*lh+1
  const unsigned* y32 = (const unsigned*)y;
  unsigned* h32 = (unsigned*)h;
  float b0 = bias[2 * lh], b1 = bias[2 * lh + 1];
  float p0 = 0, p1 = 0, q0 = 0, q1 = 0;
  int stride = gridDim.x * 8;
  for (int nodeA = blockIdx.x * 8 + wv * 2; nodeA < n; nodeA += stride) {
    int nodeB = nodeA + 1;
    bool hasB = nodeB < n;
    float a0 = 0, a1 = 0, c0 = 0, c1 = 0;
    int e0 = rowptr[nodeA], f0 = rowptr[nodeA + 1];
    int e1 = hasB ? rowptr[nodeB] : 0;
    int f1 = hasB ? rowptr[nodeB + 1] : 0;
    while (e0 + 8 <= f0 && e1 + 8 <= f1) {
#pragma unroll
      for (int k = 0; k < 4; ++k) {
        int sA = colidx[e0 + 2 * k + half];
        int sB = colidx[e1 + 2 * k + half];
        unsigned dA = y32[(size_t)sA * 32 + lh];
        unsigned dB = y32[(size_t)sB * 32 + lh];
        union { unsigned u; float f; } t0, t1, t2, t3;
        t0.u = dA << 16; t1.u = dA & 0xFFFF0000u;
        t2.u = dB << 16; t3.u = dB & 0xFFFF0000u;
        a0 += t0.f; a1 += t1.f; c0 += t2.f; c1 += t3.f;
      }
      e0 += 8; e1 += 8;
    }
    for (; e0 + 8 <= f0; e0 += 8) {
#pragma unroll
      for (int k = 0; k < 4; ++k) {
        int s = colidx[e0 + 2 * k + half];
        unsigned d = y32[(size_t)s * 32 + lh];
        union { unsigned u; float f; } t0, t1;
        t0.u = d << 16; t1.u = d & 0xFFFF0000u;
        a0 += t0.f; a1 += t1.f;
      }
    }
    for (; e0 + 2 <= f0; e0 += 2) {
      int s = colidx[e0 + half];
      unsigned d = y32[(size_t)s * 32 + lh];
      union { unsigned u; float f; } t0, t1;
      t0.u = d << 16; t1.u = d & 0xFFFF0000u;
      a0 += t0.f; a1 += t1.f;
    }
    if (e0 < f0) {
      int s = colidx[e0];
      unsigned d = y32[(size_t)s * 32 + lh];
      if (half == 0) {
        union { unsigned u; float f; } t0, t1;
        t0.u = d << 16; t1.u = d & 0xFFFF0000u;
        a0 += t0.f; a1 += t1.f;
      }
    }
    for (; e1 + 8 <= f1; e1 += 8) {
#pragma unroll
      for (int k = 0; k < 4; ++k) {
        int s = colidx[e1 + 2 * k + half];
        unsigned d = y32[(size_t)s * 32 + lh];
        union { unsigned u; float f; } t0, t1;
        t0.u = d << 16; t1.u = d & 0xFFFF0000u;
        c0 += t0.f; c1 += t1.f;
      }
    }
    for (; e1 + 2 <= f1; e1 += 2) {
      int s = colidx[e1 + half];
      unsigned d = y32[(size_t)s * 32 + lh];
      union { unsigned u; float f; } t0, t1;
      t0.u = d << 16; t1.u = d & 0xFFFF0000u;
      c0 += t0.f; c1 += t1.f;
    }
    if (e1 < f1) {
      int s = colidx[e1];
      unsigned d = y32[(size_t)s * 32 + lh];
      if (half == 0) {
        union { unsigned u; float f; } t0, t1;
        t0.u = d << 16; t1.u = d & 0xFFFF0000u;
        c0 += t0.f; c1 += t1.f;
      }
    }
    a0 += __shfl_xor(a0, 32); a1 += __shfl_xor(a1, 32);
    c0 += __shfl_xor(c0, 32); c1 += __shfl_xor(c1, 32);
    int node = half ? nodeB : nodeA;
    float u0 = half ? c0 : a0;
    float u1 = half ? c1 : a1;
    if (half == 0 || hasB) {
      unsigned sd = y32[(size_t)node * 32 + lh];
      union { unsigned u; float f; } s0, s1;
      s0.u = sd << 16; s1.u = sd & 0xFFFF0000u;
      float v0 = u0 + s0.f + b0;
      float v1 = u1 + s1.f + b1;
      union { bf16 hh[2]; unsigned u; } o;
      o.hh[0] = (bf16)v0; o.hh[1] = (bf16)v1;
      h32[(size_t)node * 32 + lh] = o.u;
      p0 += v0; q0 += v0 * v0;
      p1 += v1; q1 += v1 * v1;
    }
  }
  atomicAdd(&s_sum[2 * lh], p0); atomicAdd(&s_sq[2 * lh], q0);
  atomicAdd(&s_sum[2 * lh + 1], p1); atomicAdd(&s_sq[2 * lh + 1], q1);
  __syncthreads();
  if (tid < 64) {
    atomicAdd(&stats[tid], s_sum[tid]);
    atomicAdd(&stats[64 + tid], s_sq[tid]);
  }
}

// ------- final MLP over concat [emb(deg,lab)|z1|z2|bnleaky(h2)] (320 -> 64), MFMA -------
__global__ __launch_bounds__(256) void mfma_final(
    const int* __restrict__ deg, const int* __restrict__ lab,
    const float* __restrict__ ed, const float* __restrict__ el,
    const bf16* __restrict__ z1, const bf16* __restrict__ z2,
    const bf16* __restrict__ h2, const float* __restrict__ st2,
    const float* __restrict__ g2, const float* __restrict__ be2, float inv_n,
    const float* __restrict__ fw1, const float* __restrict__ fb1,
    bf16* __restrict__ hf, float* __restrict__ stats, int n) {
  __shared__ bf16 As[64][136];
  __shared__ bf16 Bs[64][136];
  __shared__ float s_sum[64], s_sq[64], ssc[64], ssh[64];
  int tid = threadIdx.x;
  if (tid < 64) {
    s_sum[tid] = 0.f; s_sq[tid] = 0.f;
    float sc, sh;
    bn_coeffs(st2, g2, be2, inv_n, tid, sc, sh);
    ssc[tid] = sc; ssh[tid] = sh;
  }
  int nbase = blockIdx.x * 64;
  int l = tid & 63, w = tid >> 6, m = l & 15, quad = l >> 4;
  int r = tid >> 2, c = tid & 3;
  int node_r = nbase + r;
  f32x4 acc[4] = {{0.f, 0.f, 0.f, 0.f}, {0.f, 0.f, 0.f, 0.f},
                  {0.f, 0.f, 0.f, 0.f}, {0.f, 0.f, 0.f, 0.f}};

#pragma unroll
  for (int seg = 0; seg < 4; ++seg) {
    __syncthreads();
    if (seg == 0) {
      union { bf16 hh[32]; uint4 u[4]; } t;
      if (node_r < n) {
        int idx = (c < 2) ? deg[node_r] : lab[node_r];
        const float* srcp = (c < 2) ? (ed + (size_t)idx * 64 + c * 32)
                                    : (el + (size_t)idx * 64 + (c - 2) * 32);
#pragma unroll
        for (int j = 0; j < 8; ++j) {
          float4 f = ((const float4*)srcp)[j];
          t.hh[j * 4 + 0] = (bf16)f.x; t.hh[j * 4 + 1] = (bf16)f.y;
          t.hh[j * 4 + 2] = (bf16)f.z; t.hh[j * 4 + 3] = (bf16)f.w;
        }
      } else {
#pragma unroll
        for (int j = 0; j < 4; ++j) t.u[j] = uint4{0, 0, 0, 0};
      }
#pragma unroll
      for (int j = 0; j < 4; ++j) *(uint4*)&As[r][c * 32 + j * 8] = t.u[j];
      const float4* wp = (const float4*)(fw1 + r * 320 + c * 32);
#pragma unroll
      for (int j = 0; j < 4; ++j) {
        float4 f0 = wp[j * 2], f1 = wp[j * 2 + 1];
        union { bf16 h[8]; uint4 u; } tw;
        tw.h[0] = (bf16)f0.x; tw.h[1] = (bf16)f0.y; tw.h[2] = (bf16)f0.z; tw.h[3] = (bf16)f0.w;
        tw.h[4] = (bf16)f1.x; tw.h[5] = (bf16)f1.y; tw.h[6] = (bf16)f1.z; tw.h[7] = (bf16)f1.w;
        *(uint4*)&Bs[r][c * 32 + j * 8] = tw.u;
      }
    } else if (seg < 3) {
      const bf16* zz = (seg == 1) ? z1 : z2;
      uint4 v[2] = {};
      if (node_r < n) {
        const uint4* p = (const uint4*)(zz + (size_t)node_r * 64 + c * 16);
        v[0] = p[0]; v[1] = p[1];
      }
      *(uint4*)&As[r][c * 16] = v[0];
      *(uint4*)&As[r][c * 16 + 8] = v[1];
      const float4* wp = (const float4*)(fw1 + r * 320 + (seg == 1 ? 128 : 192) + c * 16);
#pragma unroll
      for (int j = 0; j < 2; ++j) {
        float4 f0 = wp[j * 2], f1 = wp[j * 2 + 1];
        union { bf16 h[8]; uint4 u; } t;
        t.h[0] = (bf16)f0.x; t.h[1] = (bf16)f0.y; t.h[2] = (bf16)f0.z; t.h[3] = (bf16)f0.w;
        t.h[4] = (bf16)f1.x; t.h[5] = (bf16)f1.y; t.h[6] = (bf16)f1.z; t.h[7] = (bf16)f1.w;
        *(uint4*)&Bs[r][c * 16 + j * 8] = t.u;
      }
    } else {
      union { bf16 h[16]; uint4 u[2]; } t;
      if (node_r < n) {
        const uint4* p = (const uint4*)(h2 + (size_t)node_r * 64 + c * 16);
        union { uint4 u; bf16 h[8]; } a0, a1;
        a0.u = p[0]; a1.u = p[1];
#pragma unroll
        for (int j = 0; j < 8; ++j) {
          int d = c * 16 + j;
          float v = (float)a0.h[j] * ssc[d] + ssh[d];
          v = (v >= 0.f) ? v : 0.01f * v;
          t.h[j] = (bf16)v;
        }
#pragma unroll
        for (int j = 0; j < 8; ++j) {
          int d = c * 16 + 8 + j;
          float v = (float)a1.h[j] * ssc[d] + ssh[d];
          v = (v >= 0.f) ? v : 0.01f * v;
          t.h[8 + j] = (bf16)v;
        }
      } else {
        t.u[0] = uint4{0, 0, 0, 0}; t.u[1] = uint4{0, 0, 0, 0};
      }
      *(uint4*)&As[r][c * 16] = t.u[0];
      *(uint4*)&As[r][c * 16 + 8] = t.u[1];
      const float4* wp = (const float4*)(fw1 + r * 320 + 256 + c * 16);
#pragma unroll
      for (int j = 0; j < 2; ++j) {
        float4 f0 = wp[j * 2], f1 = wp[j * 2 + 1];
        union { bf16 h[8]; uint4 u; } tw;
        tw.h[0] = (bf16)f0.x; tw.h[1] = (bf16)f0.y; tw.h[2] = (bf16)f0.z; tw.h[3] = (bf16)f0.w;
        tw.h[4] = (bf16)f1.x; tw.h[5] = (bf16)f1.y; tw.h[6] = (bf16)f1.z; tw.h[7] = (bf16)f1.w;
        *(uint4*)&Bs[r][c * 16 + j * 8] = tw.u;
      }
    }
    __syncthreads();
    int kmax = (seg == 0) ? 128 : 64;
    for (int k0 = 0; k0 < kmax; k0 += 32) {
      bf16x8 a = *(const bf16x8*)&As[w * 16 + m][k0 + quad * 8];
#pragma unroll
      for (int t = 0; t < 4; ++t) {
        bf16x8 b = *(const bf16x8*)&Bs[t * 16 + m][k0 + quad * 8];
        acc[t] = __builtin_amdgcn_mfma_f32_16x16x32_bf16(a, b, acc[t], 0, 0, 0);
      }
    }
  }

#pragma unroll
  for (int t = 0; t < 4; ++t) {
    int o = t * 16 + m;
    float bv = fb1[o];
    float s = 0.f, q = 0.f;
#pragma unroll
    for (int r4 = 0; r4 < 4; ++r4) {
      int node = nbase + w * 16 + quad * 4 + r4;
      if (node < n) {
        float v = acc[t][r4] + bv;
        hf[(size_t)node * 64 + o] = (bf16)v;
        s += v;
        q += v * v;
      }
    }
    atomicAdd(&s_sum[o], s);
    atomicAdd(&s_sq[o], q);
  }
  __syncthreads();
  if (tid < 64) {
    atomicAdd(&stats[tid], s_sum[tid]);
    atomicAdd(&stats[64 + tid], s_sq[tid]);
  }
}

// ---------------- head ----------------
__global__ __launch_bounds__(256) void final_out_kernel(
    const bf16* __restrict__ hf, const float* __restrict__ st,
    const float* __restrict__ g, const float* __restrict__ be, float inv_n,
    const float* __restrict__ fw2, const float* __restrict__ fb2,
    float* __restrict__ out, int n) {
  int lane = threadIdx.x & 63;
  int node = blockIdx.x * 4 + (threadIdx.x >> 6);
  if (node >= n) return;
  float sc, sh;
  bn_coeffs(st, g, be, inv_n, lane, sc, sh);
  float v = (float)hf[(size_t)node * 64 + lane] * sc + sh;
  v = (v >= 0.f) ? v : 0.01f * v;
  v *= fw2[lane];
#pragma unroll
  for (int off = 32; off > 0; off >>= 1) v += __shfl_xor(v, off);
  if (lane == 0) out[node] = 1.f / (1.f + expf(-(v + fb2[0])));
}

extern "C" void kernel_launch(void* const* d_in, const int* in_sizes, int n_in,
                              void* d_out, int out_size, void* d_ws, size_t ws_size,
                              hipStream_t stream) {
  const int* node_deg = (const int*)d_in[0];
  const int* node_lab = (const int*)d_in[1];
  const int* ei = (const int*)d_in[2];
  const float* emb_deg = (const float*)d_in[3];
  const float* emb_lab = (const float*)d_in[4];
  const float* w0 = (const float*)d_in[5];
  const float* b0 = (const float*)d_in[6];
  const float* g0 = (const float*)d_in[7];
  const float* be0 = (const float*)d_in[8];
  const float* w1 = (const float*)d_in[9];
  const float* b1 = (const float*)d_in[10];
  const float* g1 = (const float*)d_in[11];
  const float* be1 = (const float*)d_in[12];
  const float* w2 = (const float*)d_in[13];
  const float* b2 = (const float*)d_in[14];
  const float* g2 = (const float*)d_in[15];
  const float* be2 = (const float*)d_in[16];
  const float* fw1 = (const float*)d_in[17];
  const float* fb1 = (const float*)d_in[18];
  const float* fg = (const float*)d_in[19];
  const float* fbe = (const float*)d_in[20];
  const float* fw2 = (const float*)d_in[21];
  const float* fb2 = (const float*)d_in[22];

  const int N = in_sizes[0];
  const int E = in_sizes[2] / 2;
  const int* src = ei;
  const int* dst = ei + E;
  const int NB = (N + 63) >> 6;
  const int CH = (E + NBLK - 1) / NBLK;
  const float inv_n = 1.0f / N;

  char* ws = (char*)d_ws;
  size_t off = 0;
  auto alloc = [&](size_t bytes) {
    void* p = ws + off;
    off += (bytes + 255) & ~(size_t)255;
    return p;
  };
  bf16* z1 = (bf16*)alloc((size_t)N * 64 * 2);
  bf16* z2 = (bf16*)alloc((size_t)N * 64 * 2);
  bf16* h = (bf16*)alloc((size_t)N * 64 * 2);
  bf16* y = (bf16*)alloc((size_t)N * 64 * 2);  // reused as hf at the end
  int* packed = (int*)alloc((size_t)E * 4);
  int* colidx = (int*)alloc((size_t)E * 4);
  int* rowptr = (int*)alloc((size_t)(N + 1) * 4);
  int* cnt = (int*)alloc((size_t)NBLK * NB * 4);
  int* woff = (int*)alloc((size_t)NBLK * NB * 4);
  int* btot = (int*)alloc((size_t)NB * 4);
  int* bucketptr = (int*)alloc((size_t)(NB + 1) * 4);
  float* stats = (float*)alloc(4 * 256 * 4);

  hipMemsetAsync(stats, 0, 4 * 256 * 4, stream);

  // CSR build (bin_hist/bin_scatter at 512 blocks = 2 blocks/CU)
  bin_hist_kernel<<<NBLK, 256, 0, stream>>>(dst, cnt, E, CH, NB);
  bin_tot_kernel<<<(NB + 255) / 256, 256, 0, stream>>>(cnt, btot, NB);
  scan_buckets_kernel<<<1, 256, 0, stream>>>(btot, bucketptr, NB);
  bin_off_kernel<<<(NB + 255) / 256, 256, 0, stream>>>(cnt, bucketptr, woff, NB);
  bin_scatter_kernel<<<NBLK, 256, 0, stream>>>(src, dst, woff, packed, E, CH, NB);
  csr_finalize_kernel<<<NB, 256, 0, stream>>>(packed, bucketptr, rowptr, colidx, N, E);

  int ngrid = (N + 63) / 64;
  int ggrid = 2048;  // MUST fit co-resident: 4096 -> two dispatch waves, gather 85->127us (r11)

  // layer 0 (embedding fused into GEMM; x0 never materialized)
  mfma_gemm0<<<ngrid, 256, 0, stream>>>(node_deg, node_lab, emb_deg, emb_lab, w0, y, N);
  gather_kernel<<<ggrid, 256, 0, stream>>>(y, rowptr, colidx, b0, h, stats, N);
  // layer 1
  mfma_gemm_bn<<<ngrid, 256, 0, stream>>>(h, stats, g0, be0, inv_n, w1, z1, y, N);
  gather_kernel<<<ggrid, 256, 0, stream>>>(y, rowptr, colidx, b1, h, stats + 256, N);
  // layer 2
  mfma_gemm_bn<<<ngrid, 256, 0, stream>>>(h, stats + 256, g1, be1, inv_n, w2, z2, y, N);
  gather_kernel<<<ggrid, 256, 0, stream>>>(y, rowptr, colidx, b2, h, stats + 512, N);
  // final MLP 320 -> 64 (embedding re-gathered inline)
  mfma_final<<<ngrid, 256, 0, stream>>>(node_deg, node_lab, emb_deg, emb_lab, z1, z2, h,
                                        stats + 512, g2, be2, inv_n, fw1, fb1, y,
                                        stats + 768, N);
  final_out_kernel<<<(N + 3) / 4, 256, 0, stream>>>(y, stats + 768, fg, fbe, inv_n,
                                                    fw2, fb2, (float*)d_out, N);
}

// Round 14
// 542.270 us; speedup vs baseline: 1.0319x; 1.0319x over previous
//
#include <hip/hip_runtime.h>
#include <math.h>

typedef __bf16 bf16;
typedef __attribute__((ext_vector_type(8))) __bf16 bf16x8;
typedef __attribute__((ext_vector_type(4))) float f32x4;

#define NBLK 128      // edge-partition blocks for binning (128 optimal: r13's 512 regressed)
#define NB_MAX 1600   // max buckets (N/64); N=100000 -> 1563

__device__ __forceinline__ void bn_coeffs(const float* st, const float* g,
                                          const float* be, float inv_n, int d,
                                          float& sc, float& sh) {
  float mean = st[d] * inv_n;
  float var = st[64 + d] * inv_n - mean * mean;
  sc = g[d] * rsqrtf(var + 1e-5f);
  sh = be[d] - mean * sc;
}

// ---------------- edge binning (bucket = dst>>6) ----------------
__global__ __launch_bounds__(256) void bin_hist_kernel(const int* __restrict__ dst,
                                                       int* __restrict__ cnt,
                                                       int E, int ch, int nb) {
  __shared__ int lcnt[NB_MAX];
  int tid = threadIdx.x, blk = blockIdx.x;
  for (int t = tid; t < nb; t += 256) lcnt[t] = 0;
  __syncthreads();
  int base = blk * ch, eend = min(E, base + ch);
  for (int e = base + tid; e < eend; e += 256) atomicAdd(&lcnt[dst[e] >> 6], 1);
  __syncthreads();
  for (int t = tid; t < nb; t += 256) cnt[blk * nb + t] = lcnt[t];
}

__global__ __launch_bounds__(256) void bin_tot_kernel(const int* __restrict__ cnt,
                                                      int* __restrict__ tot, int nb) {
  int b = blockIdx.x * 256 + threadIdx.x;
  if (b >= nb) return;
  int s = 0;
  for (int blk = 0; blk < NBLK; ++blk) s += cnt[blk * nb + b];
  tot[b] = s;
}

__global__ __launch_bounds__(256) void scan_buckets_kernel(const int* __restrict__ tot,
                                                           int* __restrict__ bucketptr, int nb) {
  __shared__ int lds[256];
  int tid = threadIdx.x;
  const int CH = 7;
  int vals[CH];
  int s = 0;
#pragma unroll
  for (int k = 0; k < CH; ++k) {
    int i = tid * CH + k;
    vals[k] = (i < nb) ? tot[i] : 0;
    s += vals[k];
  }
  lds[tid] = s;
  __syncthreads();
  for (int off = 1; off < 256; off <<= 1) {
    int v = (tid >= off) ? lds[tid - off] : 0;
    __syncthreads();
    lds[tid] += v;
    __syncthreads();
  }
  int run = lds[tid] - s;
  if (tid == 0) bucketptr[0] = 0;
#pragma unroll
  for (int k = 0; k < CH; ++k) {
    int i = tid * CH + k;
    run += vals[k];
    if (i < nb) bucketptr[i + 1] = run;
  }
}

__global__ __launch_bounds__(256) void bin_off_kernel(const int* __restrict__ cnt,
                                                      const int* __restrict__ bucketptr,
                                                      int* __restrict__ woff, int nb) {
  int b = blockIdx.x * 256 + threadIdx.x;
  if (b >= nb) return;
  int run = bucketptr[b];
  for (int blk = 0; blk < NBLK; ++blk) {
    woff[blk * nb + b] = run;
    run += cnt[blk * nb + b];
  }
}

__global__ __launch_bounds__(256) void bin_scatter_kernel(const int* __restrict__ src,
                                                          const int* __restrict__ dst,
                                                          const int* __restrict__ woff,
                                                          int* __restrict__ packed,
                                                          int E, int ch, int nb) {
  __shared__ int cur[NB_MAX];
  int tid = threadIdx.x, blk = blockIdx.x;
  for (int t = tid; t < nb; t += 256) cur[t] = woff[blk * nb + t];
  __syncthreads();
  int base = blk * ch, eend = min(E, base + ch);
  for (int e = base + tid; e < eend; e += 256) {
    int d = dst[e], s = src[e];
    int pos = atomicAdd(&cur[d >> 6], 1);
    packed[pos] = ((d & 63) << 17) | s;
  }
}

__global__ __launch_bounds__(256) void csr_finalize_kernel(
    const int* __restrict__ packed, const int* __restrict__ bucketptr,
    int* __restrict__ rowptr, int* __restrict__ colidx, int n, int E) {
  __shared__ int hist[64], offs[64];
  int tid = threadIdx.x, b = blockIdx.x;
  if (tid < 64) hist[tid] = 0;
  __syncthreads();
  int beg = bucketptr[b], end = bucketptr[b + 1];
  for (int e = beg + tid; e < end; e += 256) atomicAdd(&hist[packed[e] >> 17], 1);
  __syncthreads();
  if (tid == 0) {
    int run = 0;
    for (int j = 0; j < 64; ++j) { offs[j] = run; run += hist[j]; }
  }
  __syncthreads();
  if (tid < 64) {
    int idx = b * 64 + tid;
    if (idx < n) rowptr[idx] = beg + offs[tid];
    hist[tid] = offs[tid];
  }
  if (b == 0 && tid == 64) rowptr[n] = E;
  __syncthreads();
  for (int e = beg + tid; e < end; e += 256) {
    int w = packed[e];
    int pos = atomicAdd(&hist[w >> 17], 1);
    colidx[beg + pos] = w & 0x1FFFF;
  }
}

// ------- MFMA GEMM 0 with fused embedding (no x0 materialization) -------
__global__ __launch_bounds__(256) void mfma_gemm0(
    const int* __restrict__ deg, const int* __restrict__ lab,
    const float* __restrict__ ed, const float* __restrict__ el,
    const float* __restrict__ W, bf16* __restrict__ y, int n) {
  __shared__ bf16 As[64][136];
  __shared__ bf16 Bs[64][136];
  int tid = threadIdx.x;
  int nbase = blockIdx.x * 64;
  {
    int r = tid >> 2, c = tid & 3;
    int node = nbase + r;
    union { bf16 hh[32]; uint4 u[4]; } t;
    if (node < n) {
      int idx = (c < 2) ? deg[node] : lab[node];
      const float* srcp = (c < 2) ? (ed + (size_t)idx * 64 + c * 32)
                                  : (el + (size_t)idx * 64 + (c - 2) * 32);
#pragma unroll
      for (int j = 0; j < 8; ++j) {
        float4 f = ((const float4*)srcp)[j];
        t.hh[j * 4 + 0] = (bf16)f.x; t.hh[j * 4 + 1] = (bf16)f.y;
        t.hh[j * 4 + 2] = (bf16)f.z; t.hh[j * 4 + 3] = (bf16)f.w;
      }
    } else {
#pragma unroll
      for (int j = 0; j < 4; ++j) t.u[j] = uint4{0, 0, 0, 0};
    }
#pragma unroll
    for (int j = 0; j < 4; ++j) *(uint4*)&As[r][c * 32 + j * 8] = t.u[j];
    const float4* wp = (const float4*)(W + r * 128 + c * 32);
#pragma unroll
    for (int j = 0; j < 4; ++j) {
      float4 f0 = wp[j * 2], f1 = wp[j * 2 + 1];
      union { bf16 h[8]; uint4 u; } tw;
      tw.h[0] = (bf16)f0.x; tw.h[1] = (bf16)f0.y; tw.h[2] = (bf16)f0.z; tw.h[3] = (bf16)f0.w;
      tw.h[4] = (bf16)f1.x; tw.h[5] = (bf16)f1.y; tw.h[6] = (bf16)f1.z; tw.h[7] = (bf16)f1.w;
      *(uint4*)&Bs[r][c * 32 + j * 8] = tw.u;
    }
  }
  __syncthreads();
  int l = tid & 63, w = tid >> 6, m = l & 15, quad = l >> 4;
  f32x4 acc[4] = {{0.f, 0.f, 0.f, 0.f}, {0.f, 0.f, 0.f, 0.f},
                  {0.f, 0.f, 0.f, 0.f}, {0.f, 0.f, 0.f, 0.f}};
#pragma unroll
  for (int k0 = 0; k0 < 128; k0 += 32) {
    bf16x8 a = *(const bf16x8*)&As[w * 16 + m][k0 + quad * 8];
#pragma unroll
    for (int t = 0; t < 4; ++t) {
      bf16x8 b = *(const bf16x8*)&Bs[t * 16 + m][k0 + quad * 8];
      acc[t] = __builtin_amdgcn_mfma_f32_16x16x32_bf16(a, b, acc[t], 0, 0, 0);
    }
  }
#pragma unroll
  for (int t = 0; t < 4; ++t)
#pragma unroll
    for (int r4 = 0; r4 < 4; ++r4) {
      int node = nbase + w * 16 + quad * 4 + r4;
      if (node < n) y[(size_t)node * 64 + t * 16 + m] = (bf16)acc[t][r4];
    }
}

// ------- MFMA GEMM (layers 1,2) -------
__global__ __launch_bounds__(256) void mfma_gemm_bn(
    const bf16* __restrict__ hin, const float* __restrict__ st,
    const float* __restrict__ g, const float* __restrict__ be, float inv_n,
    const float* __restrict__ W, bf16* __restrict__ z,
    bf16* __restrict__ y, int n) {
  __shared__ bf16 As[64][72];
  __shared__ bf16 Bs[64][72];
  __shared__ float ssc[64], ssh[64];
  int tid = threadIdx.x;
  int nbase = blockIdx.x * 64;
  if (tid < 64) {
    float sc, sh;
    bn_coeffs(st, g, be, inv_n, tid, sc, sh);
    ssc[tid] = sc; ssh[tid] = sh;
  }
  __syncthreads();
  {
    int r = tid >> 2, c = tid & 3;
    int node = nbase + r;
    union { bf16 h[16]; uint4 u[2]; } t;
    if (node < n) {
      const uint4* p = (const uint4*)(hin + (size_t)node * 64 + c * 16);
      union { uint4 u; bf16 h[8]; } a0, a1;
      a0.u = p[0]; a1.u = p[1];
#pragma unroll
      for (int j = 0; j < 8; ++j) {
        int d = c * 16 + j;
        float v = (float)a0.h[j] * ssc[d] + ssh[d];
        v = (v >= 0.f) ? v : 0.01f * v;
        t.h[j] = (bf16)v;
      }
#pragma unroll
      for (int j = 0; j < 8; ++j) {
        int d = c * 16 + 8 + j;
        float v = (float)a1.h[j] * ssc[d] + ssh[d];
        v = (v >= 0.f) ? v : 0.01f * v;
        t.h[8 + j] = (bf16)v;
      }
      *(uint4*)(z + (size_t)node * 64 + c * 16) = t.u[0];
      *(uint4*)(z + (size_t)node * 64 + c * 16 + 8) = t.u[1];
    } else {
      t.u[0] = uint4{0, 0, 0, 0}; t.u[1] = uint4{0, 0, 0, 0};
    }
    *(uint4*)&As[r][c * 16] = t.u[0];
    *(uint4*)&As[r][c * 16 + 8] = t.u[1];
    const float4* wp = (const float4*)(W + r * 64 + c * 16);
#pragma unroll
    for (int j = 0; j < 2; ++j) {
      float4 f0 = wp[j * 2], f1 = wp[j * 2 + 1];
      union { bf16 h[8]; uint4 u; } tw;
      tw.h[0] = (bf16)f0.x; tw.h[1] = (bf16)f0.y; tw.h[2] = (bf16)f0.z; tw.h[3] = (bf16)f0.w;
      tw.h[4] = (bf16)f1.x; tw.h[5] = (bf16)f1.y; tw.h[6] = (bf16)f1.z; tw.h[7] = (bf16)f1.w;
      *(uint4*)&Bs[r][c * 16 + j * 8] = tw.u;
    }
  }
  __syncthreads();
  int l = tid & 63, w = tid >> 6, m = l & 15, quad = l >> 4;
  f32x4 acc[4] = {{0.f, 0.f, 0.f, 0.f}, {0.f, 0.f, 0.f, 0.f},
                  {0.f, 0.f, 0.f, 0.f}, {0.f, 0.f, 0.f, 0.f}};
#pragma unroll
  for (int k0 = 0; k0 < 64; k0 += 32) {
    bf16x8 a = *(const bf16x8*)&As[w * 16 + m][k0 + quad * 8];
#pragma unroll
    for (int t = 0; t < 4; ++t) {
      bf16x8 b = *(const bf16x8*)&Bs[t * 16 + m][k0 + quad * 8];
      acc[t] = __builtin_amdgcn_mfma_f32_16x16x32_bf16(a, b, acc[t], 0, 0, 0);
    }
  }
#pragma unroll
  for (int t = 0; t < 4; ++t)
#pragma unroll
    for (int r4 = 0; r4 < 4; ++r4) {
      int node = nbase + w * 16 + quad * 4 + r4;
      if (node < n) y[(size_t)node * 64 + t * 16 + m] = (bf16)acc[t][r4];
    }
}

// ------- gather: dual-node interleave, each load serves 2 edges (r8 proven version) -------
__global__ __launch_bounds__(256) void gather_kernel(
    const bf16* __restrict__ y, const int* __restrict__ rowptr,
    const int* __restrict__ colidx, const float* __restrict__ bias,
    bf16* __restrict__ h, float* __restrict__ stats, int n) {
  __shared__ float s_sum[64], s_sq[64];
  int tid = threadIdx.x;
  if (tid < 64) { s_sum[tid] = 0.f; s_sq[tid] = 0.f; }
  __syncthreads();
  int lane = tid & 63, wv = tid >> 6;
  int half = lane >> 5;  // which edge of the pair
  int lh = lane & 31;    // dim pair 2*lh, 2*lh+1
  const unsigned* y32 = (const unsigned*)y;
  unsigned* h32 = (unsigned*)h;
  float b0 = bias[2 * lh], b1 = bias[2 * lh + 1];
  float p0 = 0, p1 = 0, q0 = 0, q1 = 0;
  int stride = gridDim.x * 8;
  for (int nodeA = blockIdx.x * 8 + wv * 2; nodeA < n; nodeA += stride) {
    int nodeB = nodeA + 1;
    bool hasB = nodeB < n;
    float a0 = 0, a1 = 0, c0 = 0, c1 = 0;
    int e0 = rowptr[nodeA], f0 = rowptr[nodeA + 1];
    int e1 = hasB ? rowptr[nodeB] : 0;
    int f1 = hasB ? rowptr[nodeB + 1] : 0;
    while (e0 + 8 <= f0 && e1 + 8 <= f1) {
#pragma unroll
      for (int k = 0; k < 4; ++k) {
        int sA = colidx[e0 + 2 * k + half];
        int sB = colidx[e1 + 2 * k + half];
        unsigned dA = y32[(size_t)sA * 32 + lh];
        unsigned dB = y32[(size_t)sB * 32 + lh];
        union { unsigned u; float f; } t0, t1, t2, t3;
        t0.u = dA << 16; t1.u = dA & 0xFFFF0000u;
        t2.u = dB << 16; t3.u = dB & 0xFFFF0000u;
        a0 += t0.f; a1 += t1.f; c0 += t2.f; c1 += t3.f;
      }
      e0 += 8; e1 += 8;
    }
    for (; e0 + 8 <= f0; e0 += 8) {
#pragma unroll
      for (int k = 0; k < 4; ++k) {
        int s = colidx[e0 + 2 * k + half];
        unsigned d = y32[(size_t)s * 32 + lh];
        union { unsigned u; float f; } t0, t1;
        t0.u = d << 16; t1.u = d & 0xFFFF0000u;
        a0 += t0.f; a1 += t1.f;
      }
    }
    for (; e0 + 2 <= f0; e0 += 2) {
      int s = colidx[e0 + half];
      unsigned d = y32[(size_t)s * 32 + lh];
      union { unsigned u; float f; } t0, t1;
      t0.u = d << 16; t1.u = d & 0xFFFF0000u;
      a0 += t0.f; a1 += t1.f;
    }
    if (e0 < f0) {
      int s = colidx[e0];
      unsigned d = y32[(size_t)s * 32 + lh];
      if (half == 0) {
        union { unsigned u; float f; } t0, t1;
        t0.u = d << 16; t1.u = d & 0xFFFF0000u;
        a0 += t0.f; a1 += t1.f;
      }
    }
    for (; e1 + 8 <= f1; e1 += 8) {
#pragma unroll
      for (int k = 0; k < 4; ++k) {
        int s = colidx[e1 + 2 * k + half];
        unsigned d = y32[(size_t)s * 32 + lh];
        union { unsigned u; float f; } t0, t1;
        t0.u = d << 16; t1.u = d & 0xFFFF0000u;
        c0 += t0.f; c1 += t1.f;
      }
    }
    for (; e1 + 2 <= f1; e1 += 2) {
      int s = colidx[e1 + half];
      unsigned d = y32[(size_t)s * 32 + lh];
      union { unsigned u; float f; } t0, t1;
      t0.u = d << 16; t1.u = d & 0xFFFF0000u;
      c0 += t0.f; c1 += t1.f;
    }
    if (e1 < f1) {
      int s = colidx[e1];
      unsigned d = y32[(size_t)s * 32 + lh];
      if (half == 0) {
        union { unsigned u; float f; } t0, t1;
        t0.u = d << 16; t1.u = d & 0xFFFF0000u;
        c0 += t0.f; c1 += t1.f;
      }
    }
    a0 += __shfl_xor(a0, 32); a1 += __shfl_xor(a1, 32);
    c0 += __shfl_xor(c0, 32); c1 += __shfl_xor(c1, 32);
    int node = half ? nodeB : nodeA;
    float u0 = half ? c0 : a0;
    float u1 = half ? c1 : a1;
    if (half == 0 || hasB) {
      unsigned sd = y32[(size_t)node * 32 + lh];
      union { unsigned u; float f; } s0, s1;
      s0.u = sd << 16; s1.u = sd & 0xFFFF0000u;
      float v0 = u0 + s0.f + b0;
      float v1 = u1 + s1.f + b1;
      union { bf16 hh[2]; unsigned u; } o;
      o.hh[0] = (bf16)v0; o.hh[1] = (bf16)v1;
      h32[(size_t)node * 32 + lh] = o.u;
      p0 += v0; q0 += v0 * v0;
      p1 += v1; q1 += v1 * v1;
    }
  }
  atomicAdd(&s_sum[2 * lh], p0); atomicAdd(&s_sq[2 * lh], q0);
  atomicAdd(&s_sum[2 * lh + 1], p1); atomicAdd(&s_sq[2 * lh + 1], q1);
  __syncthreads();
  if (tid < 64) {
    atomicAdd(&stats[tid], s_sum[tid]);
    atomicAdd(&stats[64 + tid], s_sq[tid]);
  }
}

// ------- final MLP over concat [emb(deg,lab)|z1|z2|bnleaky(h2)] (320 -> 64), MFMA -------
__global__ __launch_bounds__(256) void mfma_final(
    const int* __restrict__ deg, const int* __restrict__ lab,
    const float* __restrict__ ed, const float* __restrict__ el,
    const bf16* __restrict__ z1, const bf16* __restrict__ z2,
    const bf16* __restrict__ h2, const float* __restrict__ st2,
    const float* __restrict__ g2, const float* __restrict__ be2, float inv_n,
    const float* __restrict__ fw1, const float* __restrict__ fb1,
    bf16* __restrict__ hf, float* __restrict__ stats, int n) {
  __shared__ bf16 As[64][136];
  __shared__ bf16 Bs[64][136];
  __shared__ float s_sum[64], s_sq[64], ssc[64], ssh[64];
  int tid = threadIdx.x;
  if (tid < 64) {
    s_sum[tid] = 0.f; s_sq[tid] = 0.f;
    float sc, sh;
    bn_coeffs(st2, g2, be2, inv_n, tid, sc, sh);
    ssc[tid] = sc; ssh[tid] = sh;
  }
  int nbase = blockIdx.x * 64;
  int l = tid & 63, w = tid >> 6, m = l & 15, quad = l >> 4;
  int r = tid >> 2, c = tid & 3;
  int node_r = nbase + r;
  f32x4 acc[4] = {{0.f, 0.f, 0.f, 0.f}, {0.f, 0.f, 0.f, 0.f},
                  {0.f, 0.f, 0.f, 0.f}, {0.f, 0.f, 0.f, 0.f}};

#pragma unroll
  for (int seg = 0; seg < 4; ++seg) {
    __syncthreads();
    if (seg == 0) {
      union { bf16 hh[32]; uint4 u[4]; } t;
      if (node_r < n) {
        int idx = (c < 2) ? deg[node_r] : lab[node_r];
        const float* srcp = (c < 2) ? (ed + (size_t)idx * 64 + c * 32)
                                    : (el + (size_t)idx * 64 + (c - 2) * 32);
#pragma unroll
        for (int j = 0; j < 8; ++j) {
          float4 f = ((const float4*)srcp)[j];
          t.hh[j * 4 + 0] = (bf16)f.x; t.hh[j * 4 + 1] = (bf16)f.y;
          t.hh[j * 4 + 2] = (bf16)f.z; t.hh[j * 4 + 3] = (bf16)f.w;
        }
      } else {
#pragma unroll
        for (int j = 0; j < 4; ++j) t.u[j] = uint4{0, 0, 0, 0};
      }
#pragma unroll
      for (int j = 0; j < 4; ++j) *(uint4*)&As[r][c * 32 + j * 8] = t.u[j];
      const float4* wp = (const float4*)(fw1 + r * 320 + c * 32);
#pragma unroll
      for (int j = 0; j < 4; ++j) {
        float4 f0 = wp[j * 2], f1 = wp[j * 2 + 1];
        union { bf16 h[8]; uint4 u; } tw;
        tw.h[0] = (bf16)f0.x; tw.h[1] = (bf16)f0.y; tw.h[2] = (bf16)f0.z; tw.h[3] = (bf16)f0.w;
        tw.h[4] = (bf16)f1.x; tw.h[5] = (bf16)f1.y; tw.h[6] = (bf16)f1.z; tw.h[7] = (bf16)f1.w;
        *(uint4*)&Bs[r][c * 32 + j * 8] = tw.u;
      }
    } else if (seg < 3) {
      const bf16* zz = (seg == 1) ? z1 : z2;
      uint4 v[2] = {};
      if (node_r < n) {
        const uint4* p = (const uint4*)(zz + (size_t)node_r * 64 + c * 16);
        v[0] = p[0]; v[1] = p[1];
      }
      *(uint4*)&As[r][c * 16] = v[0];
      *(uint4*)&As[r][c * 16 + 8] = v[1];
      const float4* wp = (const float4*)(fw1 + r * 320 + (seg == 1 ? 128 : 192) + c * 16);
#pragma unroll
      for (int j = 0; j < 2; ++j) {
        float4 f0 = wp[j * 2], f1 = wp[j * 2 + 1];
        union { bf16 h[8]; uint4 u; } t;
        t.h[0] = (bf16)f0.x; t.h[1] = (bf16)f0.y; t.h[2] = (bf16)f0.z; t.h[3] = (bf16)f0.w;
        t.h[4] = (bf16)f1.x; t.h[5] = (bf16)f1.y; t.h[6] = (bf16)f1.z; t.h[7] = (bf16)f1.w;
        *(uint4*)&Bs[r][c * 16 + j * 8] = t.u;
      }
    } else {
      union { bf16 h[16]; uint4 u[2]; } t;
      if (node_r < n) {
        const uint4* p = (const uint4*)(h2 + (size_t)node_r * 64 + c * 16);
        union { uint4 u; bf16 h[8]; } a0, a1;
        a0.u = p[0]; a1.u = p[1];
#pragma unroll
        for (int j = 0; j < 8; ++j) {
          int d = c * 16 + j;
          float v = (float)a0.h[j] * ssc[d] + ssh[d];
          v = (v >= 0.f) ? v : 0.01f * v;
          t.h[j] = (bf16)v;
        }
#pragma unroll
        for (int j = 0; j < 8; ++j) {
          int d = c * 16 + 8 + j;
          float v = (float)a1.h[j] * ssc[d] + ssh[d];
          v = (v >= 0.f) ? v : 0.01f * v;
          t.h[8 + j] = (bf16)v;
        }
      } else {
        t.u[0] = uint4{0, 0, 0, 0}; t.u[1] = uint4{0, 0, 0, 0};
      }
      *(uint4*)&As[r][c * 16] = t.u[0];
      *(uint4*)&As[r][c * 16 + 8] = t.u[1];
      const float4* wp = (const float4*)(fw1 + r * 320 + 256 + c * 16);
#pragma unroll
      for (int j = 0; j < 2; ++j) {
        float4 f0 = wp[j * 2], f1 = wp[j * 2 + 1];
        union { bf16 h[8]; uint4 u; } tw;
        tw.h[0] = (bf16)f0.x; tw.h[1] = (bf16)f0.y; tw.h[2] = (bf16)f0.z; tw.h[3] = (bf16)f0.w;
        tw.h[4] = (bf16)f1.x; tw.h[5] = (bf16)f1.y; tw.h[6] = (bf16)f1.z; tw.h[7] = (bf16)f1.w;
        *(uint4*)&Bs[r][c * 16 + j * 8] = tw.u;
      }
    }
    __syncthreads();
    int kmax = (seg == 0) ? 128 : 64;
    for (int k0 = 0; k0 < kmax; k0 += 32) {
      bf16x8 a = *(const bf16x8*)&As[w * 16 + m][k0 + quad * 8];
#pragma unroll
      for (int t = 0; t < 4; ++t) {
        bf16x8 b = *(const bf16x8*)&Bs[t * 16 + m][k0 + quad * 8];
        acc[t] = __builtin_amdgcn_mfma_f32_16x16x32_bf16(a, b, acc[t], 0, 0, 0);
      }
    }
  }

#pragma unroll
  for (int t = 0; t < 4; ++t) {
    int o = t * 16 + m;
    float bv = fb1[o];
    float s = 0.f, q = 0.f;
#pragma unroll
    for (int r4 = 0; r4 < 4; ++r4) {
      int node = nbase + w * 16 + quad * 4 + r4;
      if (node < n) {
        float v = acc[t][r4] + bv;
        hf[(size_t)node * 64 + o] = (bf16)v;
        s += v;
        q += v * v;
      }
    }
    atomicAdd(&s_sum[o], s);
    atomicAdd(&s_sq[o], q);
  }
  __syncthreads();
  if (tid < 64) {
    atomicAdd(&stats[tid], s_sum[tid]);
    atomicAdd(&stats[64 + tid], s_sq[tid]);
  }
}

// ---------------- head ----------------
__global__ __launch_bounds__(256) void final_out_kernel(
    const bf16* __restrict__ hf, const float* __restrict__ st,
    const float* __restrict__ g, const float* __restrict__ be, float inv_n,
    const float* __restrict__ fw2, const float* __restrict__ fb2,
    float* __restrict__ out, int n) {
  int lane = threadIdx.x & 63;
  int node = blockIdx.x * 4 + (threadIdx.x >> 6);
  if (node >= n) return;
  float sc, sh;
  bn_coeffs(st, g, be, inv_n, lane, sc, sh);
  float v = (float)hf[(size_t)node * 64 + lane] * sc + sh;
  v = (v >= 0.f) ? v : 0.01f * v;
  v *= fw2[lane];
#pragma unroll
  for (int off = 32; off > 0; off >>= 1) v += __shfl_xor(v, off);
  if (lane == 0) out[node] = 1.f / (1.f + expf(-(v + fb2[0])));
}

extern "C" void kernel_launch(void* const* d_in, const int* in_sizes, int n_in,
                              void* d_out, int out_size, void* d_ws, size_t ws_size,
                              hipStream_t stream) {
  const int* node_deg = (const int*)d_in[0];
  const int* node_lab = (const int*)d_in[1];
  const int* ei = (const int*)d_in[2];
  const float* emb_deg = (const float*)d_in[3];
  const float* emb_lab = (const float*)d_in[4];
  const float* w0 = (const float*)d_in[5];
  const float* b0 = (const float*)d_in[6];
  const float* g0 = (const float*)d_in[7];
  const float* be0 = (const float*)d_in[8];
  const float* w1 = (const float*)d_in[9];
  const float* b1 = (const float*)d_in[10];
  const float* g1 = (const float*)d_in[11];
  const float* be1 = (const float*)d_in[12];
  const float* w2 = (const float*)d_in[13];
  const float* b2 = (const float*)d_in[14];
  const float* g2 = (const float*)d_in[15];
  const float* be2 = (const float*)d_in[16];
  const float* fw1 = (const float*)d_in[17];
  const float* fb1 = (const float*)d_in[18];
  const float* fg = (const float*)d_in[19];
  const float* fbe = (const float*)d_in[20];
  const float* fw2 = (const float*)d_in[21];
  const float* fb2 = (const float*)d_in[22];

  const int N = in_sizes[0];
  const int E = in_sizes[2] / 2;
  const int* src = ei;
  const int* dst = ei + E;
  const int NB = (N + 63) >> 6;
  const int CH = (E + NBLK - 1) / NBLK;
  const float inv_n = 1.0f / N;

  char* ws = (char*)d_ws;
  size_t off = 0;
  auto alloc = [&](size_t bytes) {
    void* p = ws + off;
    off += (bytes + 255) & ~(size_t)255;
    return p;
  };
  bf16* z1 = (bf16*)alloc((size_t)N * 64 * 2);
  bf16* z2 = (bf16*)alloc((size_t)N * 64 * 2);
  bf16* h = (bf16*)alloc((size_t)N * 64 * 2);
  bf16* y = (bf16*)alloc((size_t)N * 64 * 2);  // reused as hf at the end
  int* packed = (int*)alloc((size_t)E * 4);
  int* colidx = (int*)alloc((size_t)E * 4);
  int* rowptr = (int*)alloc((size_t)(N + 1) * 4);
  int* cnt = (int*)alloc((size_t)NBLK * NB * 4);
  int* woff = (int*)alloc((size_t)NBLK * NB * 4);
  int* btot = (int*)alloc((size_t)NB * 4);
  int* bucketptr = (int*)alloc((size_t)(NB + 1) * 4);
  float* stats = (float*)alloc(4 * 256 * 4);

  hipMemsetAsync(stats, 0, 4 * 256 * 4, stream);

  // CSR build
  bin_hist_kernel<<<NBLK, 256, 0, stream>>>(dst, cnt, E, CH, NB);
  bin_tot_kernel<<<(NB + 255) / 256, 256, 0, stream>>>(cnt, btot, NB);
  scan_buckets_kernel<<<1, 256, 0, stream>>>(btot, bucketptr, NB);
  bin_off_kernel<<<(NB + 255) / 256, 256, 0, stream>>>(cnt, bucketptr, woff, NB);
  bin_scatter_kernel<<<NBLK, 256, 0, stream>>>(src, dst, woff, packed, E, CH, NB);
  csr_finalize_kernel<<<NB, 256, 0, stream>>>(packed, bucketptr, rowptr, colidx, N, E);

  int ngrid = (N + 63) / 64;
  int ggrid = 2048;  // MUST fit co-resident: 4096 -> two dispatch waves, gather 85->127us (r11)

  // layer 0 (embedding fused into GEMM; x0 never materialized)
  mfma_gemm0<<<ngrid, 256, 0, stream>>>(node_deg, node_lab, emb_deg, emb_lab, w0, y, N);
  gather_kernel<<<ggrid, 256, 0, stream>>>(y, rowptr, colidx, b0, h, stats, N);
  // layer 1
  mfma_gemm_bn<<<ngrid, 256, 0, stream>>>(h, stats, g0, be0, inv_n, w1, z1, y, N);
  gather_kernel<<<ggrid, 256, 0, stream>>>(y, rowptr, colidx, b1, h, stats + 256, N);
  // layer 2
  mfma_gemm_bn<<<ngrid, 256, 0, stream>>>(h, stats + 256, g1, be1, inv_n, w2, z2, y, N);
  gather_kernel<<<ggrid, 256, 0, stream>>>(y, rowptr, colidx, b2, h, stats + 512, N);
  // final MLP 320 -> 64 (embedding re-gathered inline)
  mfma_final<<<ngrid, 256, 0, stream>>>(node_deg, node_lab, emb_deg, emb_lab, z1, z2, h,
                                        stats + 512, g2, be2, inv_n, fw1, fb1, y,
                                        stats + 768, N);
  final_out_kernel<<<(N + 3) / 4, 256, 0, stream>>>(y, stats + 768, fg, fbe, inv_n,
                                                    fw2, fb2, (float*)d_out, N);
}